// Round 10
// baseline (650.042 us; speedup 1.0000x reference)
//
#include <hip/hip_runtime.h>
#include <hip/hip_bf16.h>
#include <cstdint>

#define HH 128
#define XX 128

typedef __attribute__((ext_vector_type(8))) short short8;
typedef __attribute__((ext_vector_type(4))) short short4_;
typedef __attribute__((ext_vector_type(4))) float float4_;
typedef __attribute__((ext_vector_type(8))) _Float16 half8_;
typedef __attribute__((ext_vector_type(2))) unsigned int uint2_;
typedef __attribute__((ext_vector_type(4))) unsigned int uint4_;

__device__ __forceinline__ float sigmoidf_(float x) {
  return 1.f / (1.f + __expf(-x));
}
__device__ __forceinline__ float tanhf_(float x) {
  float e = __expf(-2.f * fabsf(x));
  float t = (1.f - e) / (1.f + e);
  return copysignf(t, x);
}

// ================= CSR build =================
__global__ __launch_bounds__(256) void hist_kernel(const int* __restrict__ dst,
                                                   int* __restrict__ cnt, int E) {
  int e = blockIdx.x * 256 + threadIdx.x;
  if (e < E) atomicAdd(&cnt[dst[e]], 1);
}

__global__ __launch_bounds__(256) void scan_block_sum(const int* __restrict__ cnt,
                                                      int* __restrict__ bsum) {
  __shared__ int red[256];
  int b = blockIdx.x, t = threadIdx.x;
  int base = b * 1024 + t * 4;
  int s = cnt[base] + cnt[base + 1] + cnt[base + 2] + cnt[base + 3];
  red[t] = s;
  __syncthreads();
  for (int off = 128; off > 0; off >>= 1) {
    if (t < off) red[t] += red[t + off];
    __syncthreads();
  }
  if (t == 0) bsum[b] = red[0];
}

__global__ __launch_bounds__(256) void scan_top(const int* __restrict__ bsum,
                                                int* __restrict__ boff,
                                                int* __restrict__ row_ptr, int N,
                                                int E) {
  __shared__ int tmp[256];
  int t = threadIdx.x;
  int own = bsum[t];
  tmp[t] = own;
  __syncthreads();
  for (int off = 1; off < 256; off <<= 1) {
    int x = (t >= off) ? tmp[t - off] : 0;
    __syncthreads();
    tmp[t] += x;
    __syncthreads();
  }
  boff[t] = tmp[t] - own;  // exclusive
  if (t == 0) row_ptr[N] = E;
}

__global__ __launch_bounds__(256) void scan_fill(const int* __restrict__ cnt,
                                                 const int* __restrict__ boff,
                                                 int* __restrict__ row_ptr,
                                                 int* __restrict__ row_fill) {
  __shared__ int tsum[256];
  int b = blockIdx.x, t = threadIdx.x;
  int base = b * 1024 + t * 4;
  int v0 = cnt[base], v1 = cnt[base + 1], v2 = cnt[base + 2], v3 = cnt[base + 3];
  int s = v0 + v1 + v2 + v3;
  tsum[t] = s;
  __syncthreads();
  for (int off = 1; off < 256; off <<= 1) {
    int x = (t >= off) ? tsum[t - off] : 0;
    __syncthreads();
    tsum[t] += x;
    __syncthreads();
  }
  int excl = tsum[t] - s + boff[b];
  int p0 = excl, p1 = p0 + v0, p2 = p1 + v1, p3 = p2 + v2;
  row_ptr[base] = p0;
  row_ptr[base + 1] = p1;
  row_ptr[base + 2] = p2;
  row_ptr[base + 3] = p3;
  row_fill[base] = p0;
  row_fill[base + 1] = p1;
  row_fill[base + 2] = p2;
  row_fill[base + 3] = p3;
}

__global__ __launch_bounds__(256) void fill_kernel(const int* __restrict__ src,
                                                   const int* __restrict__ dst,
                                                   int* __restrict__ row_fill,
                                                   int* __restrict__ edge_src,
                                                   int E) {
  int e = blockIdx.x * 256 + threadIdx.x;
  if (e >= E) return;
  int pos = atomicAdd(&row_fill[dst[e]], 1);
  edge_src[pos] = src[e];
}

// ================= weight prep (f16, B-fragment order) =================
__global__ __launch_bounds__(256) void prep_kernel(
    const float* __restrict__ W_iou, const float* __restrict__ U_iou,
    const float* __restrict__ b_iou, const float* __restrict__ U_f_w,
    const float* __restrict__ U_f_b, const float* __restrict__ W_f_w,
    const float* __restrict__ b_f, unsigned short* __restrict__ Bh,
    float* __restrict__ bias) {
  int tid = blockIdx.x * 256 + threadIdx.x;  // 0..16383
  int kg = tid & 3;
  int c16 = (tid >> 2) & 15;
  int ks = (tid >> 6) & 7;
  int w = (tid >> 9) & 7;
  int g = (tid >> 12) & 3;
  int col = w * 16 + c16;
  int kbase = ks * 32 + kg * 8;
#pragma unroll
  for (int j = 0; j < 8; ++j) {
    int k = kbase + j;
    float v;
    if (g < 3) {
      v = (k < 128) ? W_iou[(size_t)(g * 128 + col) * 128 + k]
                    : U_iou[(size_t)(g * 128 + col) * 128 + (k - 128)];
    } else {
      v = (k < 128) ? W_f_w[(size_t)col * 128 + k]
                    : U_f_w[(size_t)col * 128 + (k - 128)];
    }
    Bh[(size_t)tid * 8 + j] = __builtin_bit_cast(unsigned short, (_Float16)v);
  }
  if (tid < 512) {
    int gg = tid >> 7, cc = tid & 127;
    bias[tid] = (gg < 3) ? b_iou[gg * 128 + cc] : (U_f_b[cc] + b_f[cc]);
  }
}

// ================= persistent pipelined fused kernel =================
// 256 blocks x 1024 threads (16 waves), 1 block/CU, tpb 64-node tiles each,
// double-buffered LDS 2 x 64 KB. Wave w: col-group (w&7), row-half (w>>3).
// Buffer halfs layout (base bb in {0, 32768}), swizzle off = k ^ ((node&7)<<3):
//   te [bb,+8192) ; h [bb+8192,..) ; hsum [bb+16384,..) ; csum f16 [bb+24576,..)
// Epilogue reuses buf as f32 words: oh [0,8192), oc [8192,16384).

__device__ __forceinline__ half8_ read_frag(const unsigned short* su, int baseH,
                                            int node, int kbase, int lane) {
  int k = kbase + ((lane >> 4) << 3);
  int off = k ^ ((node & 7) << 3);
  short8 s = *reinterpret_cast<const short8*>(&su[baseH + node * 128 + off]);
  return __builtin_bit_cast(half8_, s);
}

__device__ __forceinline__ int cw(int row, int col) {  // output-assembly word
  return row * 128 + (col ^ ((row & 7) << 2));
}

__device__ __forceinline__ uint4_ pack8(const float* v) {
  uint4_ r;
#pragma unroll
  for (int i = 0; i < 4; ++i)
    r[i] = __builtin_bit_cast(unsigned int,
                              __builtin_amdgcn_cvt_pkrtz(v[2 * i], v[2 * i + 1]));
  return r;
}

__global__ __launch_bounds__(1024, 4) void fused_mfma_kernel(
    const float* __restrict__ te, const float* __restrict__ h,
    const float* __restrict__ c, const int* __restrict__ row_ptr,
    const int* __restrict__ edge_src, const unsigned short* __restrict__ Bh,
    const float* __restrict__ bias, float* __restrict__ out_h,
    float* __restrict__ out_c, int tpb) {
  __shared__ float4_ smem4[8192];  // 131072 bytes
  unsigned short* su = (unsigned short*)smem4;

  const int t = threadIdx.x;
  const int lane = t & 63;
  const int wave = t >> 6;   // 0..15
  const int cg = wave & 7;   // col-group
  const int mh = wave >> 3;  // row-half
  const int nl = t >> 4;     // staging row 0..63
  const int sub = t & 15;    // 8-col group within row
  const int cl = lane & 15;
  const int kq = lane >> 4;
  const int col = cg * 16 + cl;

  const float bi = bias[col];
  const float bo = bias[128 + col];
  const float bu = bias[256 + col];
  const float bf = bias[384 + col];

  const int tile0 = blockIdx.x * tpb;

  // prefetch state (regs), live across the K-loop
  float4_ pt0, pt1, ph0, ph1;
  int e0 = 0, e1 = 0, shead = 0;

  auto loadStream = [&](int tile) {
    int node = tile * 64 + nl;
    const float* tp = te + (size_t)node * XX + sub * 8;
    const float* hp = h + (size_t)node * HH + sub * 8;
    pt0 = *reinterpret_cast<const float4_*>(tp);
    pt1 = *reinterpret_cast<const float4_*>(tp + 4);
    ph0 = *reinterpret_cast<const float4_*>(hp);
    ph1 = *reinterpret_cast<const float4_*>(hp + 4);
    e0 = row_ptr[node];
    e1 = row_ptr[node + 1];
    shead = edge_src[(e0 < e1) ? e0 : 0];
  };

  auto stage = [&](int bb) {
    int off = (sub * 8) ^ ((nl & 7) << 3);
    float tv[8] = {pt0[0], pt0[1], pt0[2], pt0[3], pt1[0], pt1[1], pt1[2], pt1[3]};
    float hv[8] = {ph0[0], ph0[1], ph0[2], ph0[3], ph1[0], ph1[1], ph1[2], ph1[3]};
    *reinterpret_cast<uint4_*>(&su[bb + nl * 128 + off]) = pack8(tv);
    *reinterpret_cast<uint4_*>(&su[bb + 8192 + nl * 128 + off]) = pack8(hv);
    float hs[8] = {0.f, 0.f, 0.f, 0.f, 0.f, 0.f, 0.f, 0.f};
    float cs[8] = {0.f, 0.f, 0.f, 0.f, 0.f, 0.f, 0.f, 0.f};
    for (int e = e0; e < e1; ++e) {
      int s = (e == e0) ? shead : edge_src[e];
      const float* hp = h + (size_t)s * HH + sub * 8;
      const float* cp = c + (size_t)s * HH + sub * 8;
      float4_ a0 = *reinterpret_cast<const float4_*>(hp);
      float4_ a1 = *reinterpret_cast<const float4_*>(hp + 4);
      float4_ b0 = *reinterpret_cast<const float4_*>(cp);
      float4_ b1 = *reinterpret_cast<const float4_*>(cp + 4);
#pragma unroll
      for (int j = 0; j < 4; ++j) {
        hs[j] += a0[j];
        hs[4 + j] += a1[j];
        cs[j] += b0[j];
        cs[4 + j] += b1[j];
      }
    }
    *reinterpret_cast<uint4_*>(&su[bb + 16384 + nl * 128 + off]) = pack8(hs);
    *reinterpret_cast<uint4_*>(&su[bb + 24576 + nl * 128 + off]) = pack8(cs);
  };

  // ---- prologue ----
  loadStream(tile0);
  stage(0);
  __syncthreads();

  int cur = 0;
  for (int i = 0; i < tpb; ++i) {
    const bool have = (i + 1) < tpb;
    const int bb = cur ? 32768 : 0;
    if (have) loadStream(tile0 + i + 1);  // loads in flight through K-loop

    // ---- K-loop ----
    float4_ acc[4][2];
#pragma unroll
    for (int g = 0; g < 4; ++g)
#pragma unroll
      for (int mm = 0; mm < 2; ++mm) acc[g][mm] = (float4_){0.f, 0.f, 0.f, 0.f};

    for (int ks = 0; ks < 8; ++ks) {
      half8_ bh[4];
#pragma unroll
      for (int g = 0; g < 4; ++g) {
        size_t boff = (size_t)(((g * 8 + cg) * 8 + ks) * 512) + cl * 32 + kq * 8;
        bh[g] = __builtin_bit_cast(half8_,
                                   *reinterpret_cast<const short8*>(&Bh[boff]));
      }
      if (ks < 4) {
        int kbase = ks * 32;
#pragma unroll
        for (int mm = 0; mm < 2; ++mm) {
          half8_ ah = read_frag(su, bb, (mh * 2 + mm) * 16 + cl, kbase, lane);
#pragma unroll
          for (int g = 0; g < 4; ++g)
            acc[g][mm] = __builtin_amdgcn_mfma_f32_16x16x32_f16(
                ah, bh[g], acc[g][mm], 0, 0, 0);
        }
      } else {
        int kbase = (ks - 4) * 32;
#pragma unroll
        for (int mm = 0; mm < 2; ++mm) {
          int node = (mh * 2 + mm) * 16 + cl;
          half8_ ah = read_frag(su, bb + 16384, node, kbase, lane);
          half8_ fh = read_frag(su, bb + 8192, node, kbase, lane);
#pragma unroll
          for (int g = 0; g < 3; ++g)
            acc[g][mm] = __builtin_amdgcn_mfma_f32_16x16x32_f16(
                ah, bh[g], acc[g][mm], 0, 0, 0);
          acc[3][mm] = __builtin_amdgcn_mfma_f32_16x16x32_f16(
              fh, bh[3], acc[3][mm], 0, 0, 0);
        }
      }
    }

    // csv (c_sum f16) before buffer reuse
    float csv[2][4];
#pragma unroll
    for (int mm = 0; mm < 2; ++mm)
#pragma unroll
      for (int r = 0; r < 4; ++r) {
        int row = (mh * 2 + mm) * 16 + kq * 4 + r;
        unsigned short hb = su[bb + 24576 + row * 128 + (col ^ ((row & 7) << 3))];
        csv[mm][r] = (float)__builtin_bit_cast(_Float16, hb);
      }
    __syncthreads();  // bar1: all reads of buf bb complete

    // stage next tile into other buffer (loads overlap other waves' epilogue)
    if (have) stage(cur ? 0 : 32768);

    // epilogue: gates -> assembly into buf bb (f32 words)
    float* ow = (float*)smem4 + (bb >> 1);
#pragma unroll
    for (int mm = 0; mm < 2; ++mm)
#pragma unroll
      for (int r = 0; r < 4; ++r) {
        int rowl = (mh * 2 + mm) * 16 + kq * 4 + r;
        float ig = sigmoidf_(acc[0][mm][r] + bi);
        float og = sigmoidf_(acc[1][mm][r] + bo);
        float ug = tanhf_(acc[2][mm][r] + bu);
        float fg = sigmoidf_(acc[3][mm][r] + bf);
        float cn = fmaf(ig, ug, fg * csv[mm][r]);
        int wadr = cw(rowl, col);
        ow[wadr] = og * tanhf_(cn);
        ow[8192 + wadr] = cn;
      }
    __syncthreads();  // bar2: assembly complete

    // coalesced store of both outputs
    int node0 = (tile0 + i) * 64;
#pragma unroll
    for (int i2 = 0; i2 < 2; ++i2) {
      int q = t + i2 * 1024;  // 0..2047: 64 rows x 32 float4-chunks
      int rr = q >> 5;
      int k4 = (q & 31) * 4;
      int wadr = rr * 128 + (k4 ^ ((rr & 7) << 2));
      *reinterpret_cast<float4_*>(out_h + (size_t)(node0 + rr) * HH + k4) =
          *reinterpret_cast<const float4_*>(&ow[wadr]);
      *reinterpret_cast<float4_*>(out_c + (size_t)(node0 + rr) * HH + k4) =
          *reinterpret_cast<const float4_*>(&ow[8192 + wadr]);
    }
    cur ^= 1;
  }
}

extern "C" void kernel_launch(void* const* d_in, const int* in_sizes, int n_in,
                              void* d_out, int out_size, void* d_ws, size_t ws_size,
                              hipStream_t stream) {
  const float* te = (const float*)d_in[0];
  const float* h = (const float*)d_in[1];
  const float* c = (const float*)d_in[2];
  const int* src = (const int*)d_in[3];
  const int* dst = (const int*)d_in[4];
  const float* W_iou = (const float*)d_in[5];
  const float* U_iou = (const float*)d_in[6];
  const float* b_iou = (const float*)d_in[7];
  const float* U_f_w = (const float*)d_in[8];
  const float* U_f_b = (const float*)d_in[9];
  const float* W_f_w = (const float*)d_in[10];
  const float* b_f = (const float*)d_in[11];

  const int N = in_sizes[1] / HH;
  const int E = in_sizes[3];

  float* out_h = (float*)d_out;
  float* out_c = out_h + (size_t)N * HH;

  // workspace carve-up
  char* ws = (char*)d_ws;
  unsigned short* Bh = (unsigned short*)ws;              // 256 KB
  float* bias = (float*)(Bh + 4 * 8 * 8 * 16 * 4 * 8);   // 2 KB
  int* cnt = (int*)(bias + 512);                         // N ints
  int* row_ptr = cnt + N;                                // N+4 ints
  int* row_fill = row_ptr + N + 4;                       // N ints
  int* edge_src = row_fill + N;                          // E ints
  int* bsum = edge_src + E;                              // 256
  int* boff = bsum + 256;                                // 256

  hipMemsetAsync(cnt, 0, (size_t)N * sizeof(int), stream);

  hist_kernel<<<(E + 255) / 256, 256, 0, stream>>>(dst, cnt, E);
  scan_block_sum<<<N / 1024, 256, 0, stream>>>(cnt, bsum);
  scan_top<<<1, 256, 0, stream>>>(bsum, boff, row_ptr, N, E);
  scan_fill<<<N / 1024, 256, 0, stream>>>(cnt, boff, row_ptr, row_fill);
  fill_kernel<<<(E + 255) / 256, 256, 0, stream>>>(src, dst, row_fill, edge_src, E);

  prep_kernel<<<64, 256, 0, stream>>>(W_iou, U_iou, b_iou, U_f_w, U_f_b, W_f_w,
                                      b_f, Bh, bias);

  const int nblocks = 256;
  const int tpb = (N / 64) / nblocks;  // 16
  fused_mfma_kernel<<<nblocks, 1024, 0, stream>>>(te, h, c, row_ptr, edge_src,
                                                  Bh, bias, out_h, out_c, tpb);
}

// Round 11
// 454.486 us; speedup vs baseline: 1.4303x; 1.4303x over previous
//
#include <hip/hip_runtime.h>
#include <hip/hip_bf16.h>
#include <cstdint>

#define HH 128
#define XX 128

typedef __attribute__((ext_vector_type(8))) short short8;
typedef __attribute__((ext_vector_type(4))) float float4_;
typedef __attribute__((ext_vector_type(8))) _Float16 half8_;
typedef __attribute__((ext_vector_type(4))) unsigned int uint4_;

__device__ __forceinline__ float sigmoidf_(float x) {
  return 1.f / (1.f + __expf(-x));
}
__device__ __forceinline__ float tanhf_(float x) {
  float e = __expf(-2.f * fabsf(x));
  float t = (1.f - e) / (1.f + e);
  return copysignf(t, x);
}

// ================= CSR build =================
__global__ __launch_bounds__(256) void hist_kernel(const int* __restrict__ dst,
                                                   int* __restrict__ cnt, int E) {
  int e = blockIdx.x * 256 + threadIdx.x;
  if (e < E) atomicAdd(&cnt[dst[e]], 1);
}

__global__ __launch_bounds__(256) void scan_block_sum(const int* __restrict__ cnt,
                                                      int* __restrict__ bsum) {
  __shared__ int red[256];
  int b = blockIdx.x, t = threadIdx.x;
  int base = b * 1024 + t * 4;
  int s = cnt[base] + cnt[base + 1] + cnt[base + 2] + cnt[base + 3];
  red[t] = s;
  __syncthreads();
  for (int off = 128; off > 0; off >>= 1) {
    if (t < off) red[t] += red[t + off];
    __syncthreads();
  }
  if (t == 0) bsum[b] = red[0];
}

__global__ __launch_bounds__(256) void scan_top(const int* __restrict__ bsum,
                                                int* __restrict__ boff,
                                                int* __restrict__ row_ptr, int N,
                                                int E) {
  __shared__ int tmp[256];
  int t = threadIdx.x;
  int own = bsum[t];
  tmp[t] = own;
  __syncthreads();
  for (int off = 1; off < 256; off <<= 1) {
    int x = (t >= off) ? tmp[t - off] : 0;
    __syncthreads();
    tmp[t] += x;
    __syncthreads();
  }
  boff[t] = tmp[t] - own;  // exclusive
  if (t == 0) row_ptr[N] = E;
}

__global__ __launch_bounds__(256) void scan_fill(const int* __restrict__ cnt,
                                                 const int* __restrict__ boff,
                                                 int* __restrict__ row_ptr,
                                                 int* __restrict__ row_fill) {
  __shared__ int tsum[256];
  int b = blockIdx.x, t = threadIdx.x;
  int base = b * 1024 + t * 4;
  int v0 = cnt[base], v1 = cnt[base + 1], v2 = cnt[base + 2], v3 = cnt[base + 3];
  int s = v0 + v1 + v2 + v3;
  tsum[t] = s;
  __syncthreads();
  for (int off = 1; off < 256; off <<= 1) {
    int x = (t >= off) ? tsum[t - off] : 0;
    __syncthreads();
    tsum[t] += x;
    __syncthreads();
  }
  int excl = tsum[t] - s + boff[b];
  int p0 = excl, p1 = p0 + v0, p2 = p1 + v1, p3 = p2 + v2;
  row_ptr[base] = p0;
  row_ptr[base + 1] = p1;
  row_ptr[base + 2] = p2;
  row_ptr[base + 3] = p3;
  row_fill[base] = p0;
  row_fill[base + 1] = p1;
  row_fill[base + 2] = p2;
  row_fill[base + 3] = p3;
}

__global__ __launch_bounds__(256) void fill_kernel(const int* __restrict__ src,
                                                   const int* __restrict__ dst,
                                                   int* __restrict__ row_fill,
                                                   int* __restrict__ edge_src,
                                                   int E) {
  int e = blockIdx.x * 256 + threadIdx.x;
  if (e >= E) return;
  int pos = atomicAdd(&row_fill[dst[e]], 1);
  edge_src[pos] = src[e];
}

// ================= weight prep (f16, B-fragment order) =================
__global__ __launch_bounds__(256) void prep_kernel(
    const float* __restrict__ W_iou, const float* __restrict__ U_iou,
    const float* __restrict__ b_iou, const float* __restrict__ U_f_w,
    const float* __restrict__ U_f_b, const float* __restrict__ W_f_w,
    const float* __restrict__ b_f, unsigned short* __restrict__ Bh,
    float* __restrict__ bias) {
  int tid = blockIdx.x * 256 + threadIdx.x;  // 0..16383
  int kg = tid & 3;
  int c16 = (tid >> 2) & 15;
  int ks = (tid >> 6) & 7;
  int w = (tid >> 9) & 7;
  int g = (tid >> 12) & 3;
  int col = w * 16 + c16;
  int kbase = ks * 32 + kg * 8;
#pragma unroll
  for (int j = 0; j < 8; ++j) {
    int k = kbase + j;
    float v;
    if (g < 3) {
      v = (k < 128) ? W_iou[(size_t)(g * 128 + col) * 128 + k]
                    : U_iou[(size_t)(g * 128 + col) * 128 + (k - 128)];
    } else {
      v = (k < 128) ? W_f_w[(size_t)col * 128 + k]
                    : U_f_w[(size_t)col * 128 + (k - 128)];
    }
    Bh[(size_t)tid * 8 + j] = __builtin_bit_cast(unsigned short, (_Float16)v);
  }
  if (tid < 512) {
    int gg = tid >> 7, cc = tid & 127;
    bias[tid] = (gg < 3) ? b_iou[gg * 128 + cc] : (U_f_b[cc] + b_f[cc]);
  }
}

// ================= fused gather + MFMA GEMM + gates =================
// 64-node tile, 512 threads (8 waves), (512,4) -> 2 blocks/CU, LDS 32 KB.
// A-operands (te, h) are read DIRECTLY from global inside the K-loop
// (per-lane fragment addresses; L1/L2 absorb the 4x cross-wave redundancy).
// LDS halfs (swizzle off = k ^ ((node&7)<<3)):
//   hsum f16 [0,8192) ; csum f16 [8192,16384)
// After csv, same 32 KB is reused for f16 output assembly: oh [0,8192),
// oc [8192,16384), then stored coalesced with f16->f32 cvt.

__device__ __forceinline__ uint4_ pack8(const float* v) {
  uint4_ r;
#pragma unroll
  for (int i = 0; i < 4; ++i)
    r[i] = __builtin_bit_cast(unsigned int,
                              __builtin_amdgcn_cvt_pkrtz(v[2 * i], v[2 * i + 1]));
  return r;
}

__device__ __forceinline__ half8_ cvt8(float4_ a, float4_ b) {
  uint4_ u;
  u[0] = __builtin_bit_cast(unsigned int, __builtin_amdgcn_cvt_pkrtz(a[0], a[1]));
  u[1] = __builtin_bit_cast(unsigned int, __builtin_amdgcn_cvt_pkrtz(a[2], a[3]));
  u[2] = __builtin_bit_cast(unsigned int, __builtin_amdgcn_cvt_pkrtz(b[0], b[1]));
  u[3] = __builtin_bit_cast(unsigned int, __builtin_amdgcn_cvt_pkrtz(b[2], b[3]));
  return __builtin_bit_cast(half8_, u);
}

__device__ __forceinline__ half8_ read_frag(const unsigned short* su, int baseH,
                                            int node, int kbase, int lane) {
  int k = kbase + ((lane >> 4) << 3);
  int off = k ^ ((node & 7) << 3);
  short8 s = *reinterpret_cast<const short8*>(&su[baseH + node * 128 + off]);
  return __builtin_bit_cast(half8_, s);
}

__global__ __launch_bounds__(512, 4) void fused_mfma_kernel(
    const float* __restrict__ te, const float* __restrict__ h,
    const float* __restrict__ c, const int* __restrict__ row_ptr,
    const int* __restrict__ edge_src, const unsigned short* __restrict__ Bh,
    const float* __restrict__ bias, float* __restrict__ out_h,
    float* __restrict__ out_c) {
  __shared__ float4_ smem4[2048];  // 32768 bytes
  unsigned short* su = (unsigned short*)smem4;

  const int t = threadIdx.x;
  const int node0 = blockIdx.x * 64;

  // ---- gather phase: 8 threads per node, 16 cols each ----
  {
    const int nl = t >> 3;
    const int sub = t & 7;
    const int e0 = row_ptr[node0 + nl];
    const int e1 = row_ptr[node0 + nl + 1];
    float hs[16], cs[16];
#pragma unroll
    for (int j = 0; j < 16; ++j) {
      hs[j] = 0.f;
      cs[j] = 0.f;
    }
    for (int e = e0; e < e1; ++e) {
      int s = edge_src[e];
      const float* hp = h + (size_t)s * HH + sub * 16;
      const float* cp = c + (size_t)s * HH + sub * 16;
#pragma unroll
      for (int i = 0; i < 4; ++i) {
        float4_ hv = *reinterpret_cast<const float4_*>(hp + i * 4);
        float4_ cv = *reinterpret_cast<const float4_*>(cp + i * 4);
#pragma unroll
        for (int j = 0; j < 4; ++j) {
          hs[i * 4 + j] += hv[j];
          cs[i * 4 + j] += cv[j];
        }
      }
    }
#pragma unroll
    for (int i = 0; i < 2; ++i) {
      int off = (sub * 16 + i * 8) ^ ((nl & 7) << 3);
      *reinterpret_cast<uint4_*>(&su[nl * 128 + off]) = pack8(hs + i * 8);
      *reinterpret_cast<uint4_*>(&su[8192 + nl * 128 + off]) = pack8(cs + i * 8);
    }
  }
  __syncthreads();

  const int lane = t & 63;
  const int wave = t >> 6;
  const int wc = wave * 16;
  const int cl = lane & 15;
  const int kq = lane >> 4;
  const int col = wc + cl;

  // per-lane A-fragment bases (row = node0 + m*16 + cl, k-offset kq*8)
  const float* teF = te + (size_t)(node0 + cl) * XX + kq * 8;
  const float* hF = h + (size_t)(node0 + cl) * HH + kq * 8;

  float4_ acc[4][4];  // [gate][m]
#pragma unroll
  for (int g = 0; g < 4; ++g)
#pragma unroll
    for (int m = 0; m < 4; ++m) acc[g][m] = (float4_){0.f, 0.f, 0.f, 0.f};

  for (int ks = 0; ks < 8; ++ks) {
    half8_ bh[4];
#pragma unroll
    for (int g = 0; g < 4; ++g) {
      size_t boff = (size_t)(((g * 8 + wave) * 8 + ks) * 512) + cl * 32 + kq * 8;
      bh[g] = __builtin_bit_cast(half8_,
                                 *reinterpret_cast<const short8*>(&Bh[boff]));
    }
    if (ks < 4) {
      int kbase = ks * 32;
#pragma unroll
      for (int m = 0; m < 4; ++m) {
        const float* p = teF + (size_t)m * 16 * XX + kbase;
        half8_ ah = cvt8(*reinterpret_cast<const float4_*>(p),
                         *reinterpret_cast<const float4_*>(p + 4));
#pragma unroll
        for (int g = 0; g < 4; ++g)
          acc[g][m] = __builtin_amdgcn_mfma_f32_16x16x32_f16(ah, bh[g],
                                                             acc[g][m], 0, 0, 0);
      }
    } else {
      int kbase = (ks - 4) * 32;
#pragma unroll
      for (int m = 0; m < 4; ++m) {
        half8_ ah = read_frag(su, 0, m * 16 + cl, kbase, lane);
        const float* p = hF + (size_t)m * 16 * HH + kbase;
        half8_ fh = cvt8(*reinterpret_cast<const float4_*>(p),
                         *reinterpret_cast<const float4_*>(p + 4));
#pragma unroll
        for (int g = 0; g < 3; ++g)
          acc[g][m] = __builtin_amdgcn_mfma_f32_16x16x32_f16(ah, bh[g],
                                                             acc[g][m], 0, 0, 0);
        acc[3][m] = __builtin_amdgcn_mfma_f32_16x16x32_f16(fh, bh[3],
                                                           acc[3][m], 0, 0, 0);
      }
    }
  }

  // ---- epilogue: csv from LDS, then reuse LDS for f16 output assembly ----
  const float bi = bias[col];
  const float bo = bias[128 + col];
  const float bu = bias[256 + col];
  const float bf = bias[384 + col];
  float csv[4][4];
#pragma unroll
  for (int m = 0; m < 4; ++m)
#pragma unroll
    for (int r = 0; r < 4; ++r) {
      int row = m * 16 + kq * 4 + r;
      unsigned short hb = su[8192 + row * 128 + (col ^ ((row & 7) << 3))];
      csv[m][r] = (float)__builtin_bit_cast(_Float16, hb);
    }
  __syncthreads();  // all hsum/csum reads complete; safe to overwrite

#pragma unroll
  for (int m = 0; m < 4; ++m)
#pragma unroll
    for (int r = 0; r < 4; ++r) {
      int row = m * 16 + kq * 4 + r;
      float ig = sigmoidf_(acc[0][m][r] + bi);
      float og = sigmoidf_(acc[1][m][r] + bo);
      float ug = tanhf_(acc[2][m][r] + bu);
      float fg = sigmoidf_(acc[3][m][r] + bf);
      float cn = fmaf(ig, ug, fg * csv[m][r]);
      float hn = og * tanhf_(cn);
      int off = col ^ ((row & 7) << 3);
      su[row * 128 + off] = __builtin_bit_cast(unsigned short, (_Float16)hn);
      su[8192 + row * 128 + off] = __builtin_bit_cast(unsigned short, (_Float16)cn);
    }
  __syncthreads();

  // ---- store: coalesced, f16 -> f32 ----
#pragma unroll
  for (int i = 0; i < 4; ++i) {
    int q = t + i * 512;       // 0..2047
    int arr = q >> 10;         // 0 = h, 1 = c
    int cq = q & 1023;
    int rr = cq >> 4;          // row 0..63
    int k8 = (cq & 15) * 8;    // half-offset
    short8 v = *reinterpret_cast<const short8*>(
        &su[arr * 8192 + rr * 128 + (k8 ^ ((rr & 7) << 3))]);
    half8_ hv = __builtin_bit_cast(half8_, v);
    float4_ f0, f1;
#pragma unroll
    for (int j = 0; j < 4; ++j) {
      f0[j] = (float)hv[j];
      f1[j] = (float)hv[4 + j];
    }
    float* outp = (arr ? out_c : out_h) + (size_t)(node0 + rr) * HH + k8;
    *reinterpret_cast<float4_*>(outp) = f0;
    *reinterpret_cast<float4_*>(outp + 4) = f1;
  }
}

extern "C" void kernel_launch(void* const* d_in, const int* in_sizes, int n_in,
                              void* d_out, int out_size, void* d_ws, size_t ws_size,
                              hipStream_t stream) {
  const float* te = (const float*)d_in[0];
  const float* h = (const float*)d_in[1];
  const float* c = (const float*)d_in[2];
  const int* src = (const int*)d_in[3];
  const int* dst = (const int*)d_in[4];
  const float* W_iou = (const float*)d_in[5];
  const float* U_iou = (const float*)d_in[6];
  const float* b_iou = (const float*)d_in[7];
  const float* U_f_w = (const float*)d_in[8];
  const float* U_f_b = (const float*)d_in[9];
  const float* W_f_w = (const float*)d_in[10];
  const float* b_f = (const float*)d_in[11];

  const int N = in_sizes[1] / HH;
  const int E = in_sizes[3];

  float* out_h = (float*)d_out;
  float* out_c = out_h + (size_t)N * HH;

  // workspace carve-up
  char* ws = (char*)d_ws;
  unsigned short* Bh = (unsigned short*)ws;              // 256 KB
  float* bias = (float*)(Bh + 4 * 8 * 8 * 16 * 4 * 8);   // 2 KB
  int* cnt = (int*)(bias + 512);                         // N ints
  int* row_ptr = cnt + N;                                // N+4 ints
  int* row_fill = row_ptr + N + 4;                       // N ints
  int* edge_src = row_fill + N;                          // E ints
  int* bsum = edge_src + E;                              // 256
  int* boff = bsum + 256;                                // 256

  hipMemsetAsync(cnt, 0, (size_t)N * sizeof(int), stream);

  hist_kernel<<<(E + 255) / 256, 256, 0, stream>>>(dst, cnt, E);
  scan_block_sum<<<N / 1024, 256, 0, stream>>>(cnt, bsum);
  scan_top<<<1, 256, 0, stream>>>(bsum, boff, row_ptr, N, E);
  scan_fill<<<N / 1024, 256, 0, stream>>>(cnt, boff, row_ptr, row_fill);
  fill_kernel<<<(E + 255) / 256, 256, 0, stream>>>(src, dst, row_fill, edge_src, E);

  prep_kernel<<<64, 256, 0, stream>>>(W_iou, U_iou, b_iou, U_f_w, U_f_b, W_f_w,
                                      b_f, Bh, bias);

  fused_mfma_kernel<<<N / 64, 512, 0, stream>>>(te, h, c, row_ptr, edge_src, Bh,
                                                bias, out_h, out_c);
}

// Round 12
// 294.837 us; speedup vs baseline: 2.2048x; 1.5415x over previous
//
#include <hip/hip_runtime.h>
#include <hip/hip_bf16.h>
#include <cstdint>

#define HH 128
#define XX 128
#define RS 136  // padded LDS row stride in halfs (272 B, 16-B aligned)

typedef __attribute__((ext_vector_type(8))) short short8;
typedef __attribute__((ext_vector_type(4))) float float4_;
typedef __attribute__((ext_vector_type(8))) _Float16 half8_;
typedef __attribute__((ext_vector_type(2))) unsigned int uint2_;
typedef __attribute__((ext_vector_type(4))) unsigned int uint4_;

__device__ __forceinline__ float sigmoidf_(float x) {
  return 1.f / (1.f + __expf(-x));
}
__device__ __forceinline__ float tanhf_(float x) {
  float e = __expf(-2.f * fabsf(x));
  float t = (1.f - e) / (1.f + e);
  return copysignf(t, x);
}

// ================= CSR build =================
__global__ __launch_bounds__(256) void hist_kernel(const int* __restrict__ dst,
                                                   int* __restrict__ cnt, int E) {
  int e = blockIdx.x * 256 + threadIdx.x;
  if (e < E) atomicAdd(&cnt[dst[e]], 1);
}

__global__ __launch_bounds__(256) void scan_block_sum(const int* __restrict__ cnt,
                                                      int* __restrict__ bsum) {
  __shared__ int red[256];
  int b = blockIdx.x, t = threadIdx.x;
  int base = b * 1024 + t * 4;
  int s = cnt[base] + cnt[base + 1] + cnt[base + 2] + cnt[base + 3];
  red[t] = s;
  __syncthreads();
  for (int off = 128; off > 0; off >>= 1) {
    if (t < off) red[t] += red[t + off];
    __syncthreads();
  }
  if (t == 0) bsum[b] = red[0];
}

__global__ __launch_bounds__(256) void scan_top(const int* __restrict__ bsum,
                                                int* __restrict__ boff,
                                                int* __restrict__ row_ptr, int N,
                                                int E) {
  __shared__ int tmp[256];
  int t = threadIdx.x;
  int own = bsum[t];
  tmp[t] = own;
  __syncthreads();
  for (int off = 1; off < 256; off <<= 1) {
    int x = (t >= off) ? tmp[t - off] : 0;
    __syncthreads();
    tmp[t] += x;
    __syncthreads();
  }
  boff[t] = tmp[t] - own;  // exclusive
  if (t == 0) row_ptr[N] = E;
}

__global__ __launch_bounds__(256) void scan_fill(const int* __restrict__ cnt,
                                                 const int* __restrict__ boff,
                                                 int* __restrict__ row_ptr,
                                                 int* __restrict__ row_fill) {
  __shared__ int tsum[256];
  int b = blockIdx.x, t = threadIdx.x;
  int base = b * 1024 + t * 4;
  int v0 = cnt[base], v1 = cnt[base + 1], v2 = cnt[base + 2], v3 = cnt[base + 3];
  int s = v0 + v1 + v2 + v3;
  tsum[t] = s;
  __syncthreads();
  for (int off = 1; off < 256; off <<= 1) {
    int x = (t >= off) ? tsum[t - off] : 0;
    __syncthreads();
    tsum[t] += x;
    __syncthreads();
  }
  int excl = tsum[t] - s + boff[b];
  int p0 = excl, p1 = p0 + v0, p2 = p1 + v1, p3 = p2 + v2;
  row_ptr[base] = p0;
  row_ptr[base + 1] = p1;
  row_ptr[base + 2] = p2;
  row_ptr[base + 3] = p3;
  row_fill[base] = p0;
  row_fill[base + 1] = p1;
  row_fill[base + 2] = p2;
  row_fill[base + 3] = p3;
}

__global__ __launch_bounds__(256) void fill_kernel(const int* __restrict__ src,
                                                   const int* __restrict__ dst,
                                                   int* __restrict__ row_fill,
                                                   int* __restrict__ edge_src,
                                                   int E) {
  int e = blockIdx.x * 256 + threadIdx.x;
  if (e >= E) return;
  int pos = atomicAdd(&row_fill[dst[e]], 1);
  edge_src[pos] = src[e];
}

// ================= weight prep (f16, B-fragment order) =================
__global__ __launch_bounds__(256) void prep_kernel(
    const float* __restrict__ W_iou, const float* __restrict__ U_iou,
    const float* __restrict__ b_iou, const float* __restrict__ U_f_w,
    const float* __restrict__ U_f_b, const float* __restrict__ W_f_w,
    const float* __restrict__ b_f, unsigned short* __restrict__ Bh,
    float* __restrict__ bias) {
  int tid = blockIdx.x * 256 + threadIdx.x;  // 0..16383
  int kg = tid & 3;
  int c16 = (tid >> 2) & 15;
  int ks = (tid >> 6) & 7;
  int w = (tid >> 9) & 7;
  int g = (tid >> 12) & 3;
  int col = w * 16 + c16;
  int kbase = ks * 32 + kg * 8;
#pragma unroll
  for (int j = 0; j < 8; ++j) {
    int k = kbase + j;
    float v;
    if (g < 3) {
      v = (k < 128) ? W_iou[(size_t)(g * 128 + col) * 128 + k]
                    : U_iou[(size_t)(g * 128 + col) * 128 + (k - 128)];
    } else {
      v = (k < 128) ? W_f_w[(size_t)col * 128 + k]
                    : U_f_w[(size_t)col * 128 + (k - 128)];
    }
    Bh[(size_t)tid * 8 + j] = __builtin_bit_cast(unsigned short, (_Float16)v);
  }
  if (tid < 512) {
    int gg = tid >> 7, cc = tid & 127;
    bias[tid] = (gg < 3) ? b_iou[gg * 128 + cc] : (U_f_b[cc] + b_f[cc]);
  }
}

// ================= fused gather + MFMA GEMM + gates =================
// 64-node tile, 512 threads (8 waves), (512,4) -> 2 blocks/CU, LDS 68 KB.
// Padded rows (stride RS=136 halfs) instead of XOR swizzle: ds offsets fold
// into immediates, no per-read VALU address math.
// LDS halfs: te [0) ; h [8704) wait-- layout below:
//   te    [0,      64*RS)
//   hsum  [8704,   +64*RS)
//   h     [17408,  +64*RS)
//   csum  [26112,  +64*RS)   (f16)
// After csv: reuse as f32 words: oh [0, 8704), oc [8704, 17408).

__device__ __forceinline__ uint4_ pack8(const float* v) {
  uint4_ r;
#pragma unroll
  for (int i = 0; i < 4; ++i)
    r[i] = __builtin_bit_cast(unsigned int,
                              __builtin_amdgcn_cvt_pkrtz(v[2 * i], v[2 * i + 1]));
  return r;
}

__device__ __forceinline__ void stage4(unsigned short* su, int baseH, int node,
                                       int k4, float4_ v) {
  uint2_ u;
  u[0] = __builtin_bit_cast(unsigned int, __builtin_amdgcn_cvt_pkrtz(v[0], v[1]));
  u[1] = __builtin_bit_cast(unsigned int, __builtin_amdgcn_cvt_pkrtz(v[2], v[3]));
  *reinterpret_cast<uint2_*>(&su[baseH + node * RS + k4]) = u;
}

__device__ __forceinline__ half8_ read_frag(const unsigned short* su, int baseH,
                                            int node, int kbase, int kq) {
  short8 s =
      *reinterpret_cast<const short8*>(&su[baseH + node * RS + kbase + kq * 8]);
  return __builtin_bit_cast(half8_, s);
}

__global__ __launch_bounds__(512, 4) void fused_mfma_kernel(
    const float* __restrict__ te, const float* __restrict__ h,
    const float* __restrict__ c, const int* __restrict__ row_ptr,
    const int* __restrict__ edge_src, const unsigned short* __restrict__ Bh,
    const float* __restrict__ bias, float* __restrict__ out_h,
    float* __restrict__ out_c) {
  __shared__ float4_ smem4[4352];  // 69632 bytes
  unsigned short* su = (unsigned short*)smem4;

  const int t = threadIdx.x;
  const int node0 = blockIdx.x * 64;

  // Phase 0: start gather dependency chain EARLY (row_ptr -> edge_src ->
  // first edge's h/c rows into registers) so it overlaps phase A staging.
  const int nl = t >> 3;
  const int sub = t & 7;
  const int e0 = row_ptr[node0 + nl];
  const int e1 = row_ptr[node0 + nl + 1];
  int s0 = (e0 < e1) ? edge_src[e0] : 0;
  float4_ ph[4], pc[4];
  if (e0 < e1) {
    const float* hp = h + (size_t)s0 * HH + sub * 16;
    const float* cp = c + (size_t)s0 * HH + sub * 16;
#pragma unroll
    for (int i = 0; i < 4; ++i) {
      ph[i] = *reinterpret_cast<const float4_*>(hp + i * 4);
      pc[i] = *reinterpret_cast<const float4_*>(cp + i * 4);
    }
  }

  // Phase A: stage te and own-h (streamed, coalesced) as f16
#pragma unroll
  for (int i = 0; i < 4; ++i) {
    int q = t + i * 512;  // 0..2047 float4-chunks
    int node = q >> 5;
    int k4 = (q & 31) * 4;
    float4_ v =
        *reinterpret_cast<const float4_*>(te + (size_t)(node0 + node) * XX + k4);
    stage4(su, 0, node, k4, v);
    v = *reinterpret_cast<const float4_*>(h + (size_t)(node0 + node) * HH + k4);
    stage4(su, 17408, node, k4, v);
  }

  // Phase B: finish gather: 8 threads per node, 16 cols each.
  {
    float hs[16], cs[16];
#pragma unroll
    for (int j = 0; j < 16; ++j) {
      hs[j] = 0.f;
      cs[j] = 0.f;
    }
    if (e0 < e1) {
#pragma unroll
      for (int i = 0; i < 4; ++i)
#pragma unroll
        for (int j = 0; j < 4; ++j) {
          hs[i * 4 + j] += ph[i][j];
          cs[i * 4 + j] += pc[i][j];
        }
    }
    for (int e = e0 + 1; e < e1; ++e) {
      int s = edge_src[e];
      const float* hp = h + (size_t)s * HH + sub * 16;
      const float* cp = c + (size_t)s * HH + sub * 16;
#pragma unroll
      for (int i = 0; i < 4; ++i) {
        float4_ hv = *reinterpret_cast<const float4_*>(hp + i * 4);
        float4_ cv = *reinterpret_cast<const float4_*>(cp + i * 4);
#pragma unroll
        for (int j = 0; j < 4; ++j) {
          hs[i * 4 + j] += hv[j];
          cs[i * 4 + j] += cv[j];
        }
      }
    }
#pragma unroll
    for (int i = 0; i < 2; ++i) {
      int off = nl * RS + sub * 16 + i * 8;
      *reinterpret_cast<uint4_*>(&su[8704 + off]) = pack8(hs + i * 8);
      *reinterpret_cast<uint4_*>(&su[26112 + off]) = pack8(cs + i * 8);
    }
  }
  __syncthreads();

  const int lane = t & 63;
  const int wave = t >> 6;
  const int wc = wave * 16;  // column base (one 16-col group, all 4 gates)
  const int cl = lane & 15;
  const int kq = lane >> 4;
  const int col = wc + cl;

  float4_ acc[4][4];  // [gate][m], bias added at epilogue
#pragma unroll
  for (int g = 0; g < 4; ++g)
#pragma unroll
    for (int m = 0; m < 4; ++m) acc[g][m] = (float4_){0.f, 0.f, 0.f, 0.f};

  for (int ks = 0; ks < 8; ++ks) {
    half8_ bh[4];
#pragma unroll
    for (int g = 0; g < 4; ++g) {
      size_t boff = (size_t)(((g * 8 + wave) * 8 + ks) * 512) + cl * 32 + kq * 8;
      bh[g] = __builtin_bit_cast(half8_,
                                 *reinterpret_cast<const short8*>(&Bh[boff]));
    }
    if (ks < 4) {
      int kbase = ks * 32;
#pragma unroll
      for (int m = 0; m < 4; ++m) {
        half8_ ah = read_frag(su, 0, m * 16 + cl, kbase, kq);
#pragma unroll
        for (int g = 0; g < 4; ++g)
          acc[g][m] = __builtin_amdgcn_mfma_f32_16x16x32_f16(ah, bh[g],
                                                             acc[g][m], 0, 0, 0);
      }
    } else {
      int kbase = (ks - 4) * 32;
#pragma unroll
      for (int m = 0; m < 4; ++m) {
        half8_ ah = read_frag(su, 8704, m * 16 + cl, kbase, kq);
        half8_ fh = read_frag(su, 17408, m * 16 + cl, kbase, kq);
#pragma unroll
        for (int g = 0; g < 3; ++g)
          acc[g][m] = __builtin_amdgcn_mfma_f32_16x16x32_f16(ah, bh[g],
                                                             acc[g][m], 0, 0, 0);
        acc[3][m] = __builtin_amdgcn_mfma_f32_16x16x32_f16(fh, bh[3],
                                                           acc[3][m], 0, 0, 0);
      }
    }
  }

  // Epilogue part 1: pull c_sum (f16) + bias into regs before LDS reuse.
  const float bi = bias[col];
  const float bo = bias[128 + col];
  const float bu = bias[256 + col];
  const float bf = bias[384 + col];
  float csv[4][4];
#pragma unroll
  for (int m = 0; m < 4; ++m)
#pragma unroll
    for (int r = 0; r < 4; ++r) {
      int row = m * 16 + kq * 4 + r;
      unsigned short hb = su[26112 + row * RS + col];
      csv[m][r] = (float)__builtin_bit_cast(_Float16, hb);
    }
  __syncthreads();  // all LDS reads done; safe to reuse for output assembly

  float* oh = (float*)smem4;         // words [0, 8704): h_new rows (stride RS)
  float* oc = (float*)smem4 + 8704;  // words [8704, 17408): c_new rows

  // Epilogue part 2: gates -> padded LDS assembly.
#pragma unroll
  for (int m = 0; m < 4; ++m)
#pragma unroll
    for (int r = 0; r < 4; ++r) {
      int rowl = m * 16 + kq * 4 + r;
      float ig = sigmoidf_(acc[0][m][r] + bi);
      float og = sigmoidf_(acc[1][m][r] + bo);
      float ug = tanhf_(acc[2][m][r] + bu);
      float fg = sigmoidf_(acc[3][m][r] + bf);
      float cn = fmaf(ig, ug, fg * csv[m][r]);
      int wadr = rowl * RS + col;
      oc[wadr] = cn;
      oh[wadr] = og * tanhf_(cn);
    }
  __syncthreads();

  // Stream outputs: fully coalesced float4 rows.
#pragma unroll
  for (int i = 0; i < 4; ++i) {
    int q = t + i * 512;
    int rr = q >> 5;
    int k4 = (q & 31) * 4;
    int wadr = rr * RS + k4;
    *reinterpret_cast<float4_*>(out_h + (size_t)(node0 + rr) * HH + k4) =
        *reinterpret_cast<const float4_*>(&oh[wadr]);
    *reinterpret_cast<float4_*>(out_c + (size_t)(node0 + rr) * HH + k4) =
        *reinterpret_cast<const float4_*>(&oc[wadr]);
  }
}

extern "C" void kernel_launch(void* const* d_in, const int* in_sizes, int n_in,
                              void* d_out, int out_size, void* d_ws, size_t ws_size,
                              hipStream_t stream) {
  const float* te = (const float*)d_in[0];
  const float* h = (const float*)d_in[1];
  const float* c = (const float*)d_in[2];
  const int* src = (const int*)d_in[3];
  const int* dst = (const int*)d_in[4];
  const float* W_iou = (const float*)d_in[5];
  const float* U_iou = (const float*)d_in[6];
  const float* b_iou = (const float*)d_in[7];
  const float* U_f_w = (const float*)d_in[8];
  const float* U_f_b = (const float*)d_in[9];
  const float* W_f_w = (const float*)d_in[10];
  const float* b_f = (const float*)d_in[11];

  const int N = in_sizes[1] / HH;
  const int E = in_sizes[3];

  float* out_h = (float*)d_out;
  float* out_c = out_h + (size_t)N * HH;

  // workspace carve-up
  char* ws = (char*)d_ws;
  unsigned short* Bh = (unsigned short*)ws;              // 256 KB
  float* bias = (float*)(Bh + 4 * 8 * 8 * 16 * 4 * 8);   // 2 KB
  int* cnt = (int*)(bias + 512);                         // N ints
  int* row_ptr = cnt + N;                                // N+4 ints
  int* row_fill = row_ptr + N + 4;                       // N ints
  int* edge_src = row_fill + N;                          // E ints
  int* bsum = edge_src + E;                              // 256
  int* boff = bsum + 256;                                // 256

  hipMemsetAsync(cnt, 0, (size_t)N * sizeof(int), stream);

  hist_kernel<<<(E + 255) / 256, 256, 0, stream>>>(dst, cnt, E);
  scan_block_sum<<<N / 1024, 256, 0, stream>>>(cnt, bsum);
  scan_top<<<1, 256, 0, stream>>>(bsum, boff, row_ptr, N, E);
  scan_fill<<<N / 1024, 256, 0, stream>>>(cnt, boff, row_ptr, row_fill);
  fill_kernel<<<(E + 255) / 256, 256, 0, stream>>>(src, dst, row_fill, edge_src, E);

  prep_kernel<<<64, 256, 0, stream>>>(W_iou, U_iou, b_iou, U_f_w, U_f_b, W_f_w,
                                      b_f, Bh, bias);

  fused_mfma_kernel<<<N / 64, 512, 0, stream>>>(te, h, c, row_ptr, edge_src, Bh,
                                                bias, out_h, out_c);
}

// Round 13
// 275.298 us; speedup vs baseline: 2.3612x; 1.0710x over previous
//
#include <hip/hip_runtime.h>
#include <hip/hip_bf16.h>
#include <cstdint>

#define HH 128
#define XX 128
#define RS 136  // padded LDS row stride in halfs (272 B, 16-B aligned)

typedef __attribute__((ext_vector_type(8))) short short8;
typedef __attribute__((ext_vector_type(4))) float float4_;
typedef __attribute__((ext_vector_type(8))) _Float16 half8_;
typedef __attribute__((ext_vector_type(2))) unsigned int uint2_;
typedef __attribute__((ext_vector_type(4))) unsigned int uint4_;

__device__ __forceinline__ float sigmoidf_(float x) {
  return 1.f / (1.f + __expf(-x));
}
__device__ __forceinline__ float tanhf_(float x) {
  float e = __expf(-2.f * fabsf(x));
  float t = (1.f - e) / (1.f + e);
  return copysignf(t, x);
}

// ================= CSR build =================
__global__ __launch_bounds__(256) void hist_kernel(const int* __restrict__ dst,
                                                   int* __restrict__ cnt, int E) {
  int e = blockIdx.x * 256 + threadIdx.x;
  if (e < E) atomicAdd(&cnt[dst[e]], 1);
}

__global__ __launch_bounds__(256) void scan_block_sum(const int* __restrict__ cnt,
                                                      int* __restrict__ bsum) {
  __shared__ int red[256];
  int b = blockIdx.x, t = threadIdx.x;
  int base = b * 1024 + t * 4;
  int s = cnt[base] + cnt[base + 1] + cnt[base + 2] + cnt[base + 3];
  red[t] = s;
  __syncthreads();
  for (int off = 128; off > 0; off >>= 1) {
    if (t < off) red[t] += red[t + off];
    __syncthreads();
  }
  if (t == 0) bsum[b] = red[0];
}

__global__ __launch_bounds__(256) void scan_top(const int* __restrict__ bsum,
                                                int* __restrict__ boff,
                                                int* __restrict__ row_ptr, int N,
                                                int E) {
  __shared__ int tmp[256];
  int t = threadIdx.x;
  int own = bsum[t];
  tmp[t] = own;
  __syncthreads();
  for (int off = 1; off < 256; off <<= 1) {
    int x = (t >= off) ? tmp[t - off] : 0;
    __syncthreads();
    tmp[t] += x;
    __syncthreads();
  }
  boff[t] = tmp[t] - own;  // exclusive
  if (t == 0) row_ptr[N] = E;
}

__global__ __launch_bounds__(256) void scan_fill(const int* __restrict__ cnt,
                                                 const int* __restrict__ boff,
                                                 int* __restrict__ row_ptr,
                                                 int* __restrict__ row_fill) {
  __shared__ int tsum[256];
  int b = blockIdx.x, t = threadIdx.x;
  int base = b * 1024 + t * 4;
  int v0 = cnt[base], v1 = cnt[base + 1], v2 = cnt[base + 2], v3 = cnt[base + 3];
  int s = v0 + v1 + v2 + v3;
  tsum[t] = s;
  __syncthreads();
  for (int off = 1; off < 256; off <<= 1) {
    int x = (t >= off) ? tsum[t - off] : 0;
    __syncthreads();
    tsum[t] += x;
    __syncthreads();
  }
  int excl = tsum[t] - s + boff[b];
  int p0 = excl, p1 = p0 + v0, p2 = p1 + v1, p3 = p2 + v2;
  row_ptr[base] = p0;
  row_ptr[base + 1] = p1;
  row_ptr[base + 2] = p2;
  row_ptr[base + 3] = p3;
  row_fill[base] = p0;
  row_fill[base + 1] = p1;
  row_fill[base + 2] = p2;
  row_fill[base + 3] = p3;
}

__global__ __launch_bounds__(256) void fill_kernel(const int* __restrict__ src,
                                                   const int* __restrict__ dst,
                                                   int* __restrict__ row_fill,
                                                   int* __restrict__ edge_src,
                                                   int E) {
  int e = blockIdx.x * 256 + threadIdx.x;
  if (e >= E) return;
  int pos = atomicAdd(&row_fill[dst[e]], 1);
  edge_src[pos] = src[e];
}

// ================= weight prep (f16, B-fragment order) =================
__global__ __launch_bounds__(256) void prep_kernel(
    const float* __restrict__ W_iou, const float* __restrict__ U_iou,
    const float* __restrict__ b_iou, const float* __restrict__ U_f_w,
    const float* __restrict__ U_f_b, const float* __restrict__ W_f_w,
    const float* __restrict__ b_f, unsigned short* __restrict__ Bh,
    float* __restrict__ bias) {
  int tid = blockIdx.x * 256 + threadIdx.x;  // 0..16383
  int kg = tid & 3;
  int c16 = (tid >> 2) & 15;
  int ks = (tid >> 6) & 7;
  int w = (tid >> 9) & 7;
  int g = (tid >> 12) & 3;
  int col = w * 16 + c16;
  int kbase = ks * 32 + kg * 8;
#pragma unroll
  for (int j = 0; j < 8; ++j) {
    int k = kbase + j;
    float v;
    if (g < 3) {
      v = (k < 128) ? W_iou[(size_t)(g * 128 + col) * 128 + k]
                    : U_iou[(size_t)(g * 128 + col) * 128 + (k - 128)];
    } else {
      v = (k < 128) ? W_f_w[(size_t)col * 128 + k]
                    : U_f_w[(size_t)col * 128 + (k - 128)];
    }
    Bh[(size_t)tid * 8 + j] = __builtin_bit_cast(unsigned short, (_Float16)v);
  }
  if (tid < 512) {
    int gg = tid >> 7, cc = tid & 127;
    bias[tid] = (gg < 3) ? b_iou[gg * 128 + cc] : (U_f_b[cc] + b_f[cc]);
  }
}

// ================= fused gather + MFMA GEMM + gates =================
// 64-node tile, 512 threads (8 waves), (512,4) -> 2 blocks/CU, LDS 68 KB.
// Padded rows (stride RS=136 halfs); bias pre-loaded into MFMA accumulators;
// gather edges 1-2 warm-prefetched in phase 0; te loads + output stores are
// nontemporal to keep the h/c gather working set L2/L3-resident.
// LDS halfs:
//   te    [0,      64*RS)
//   hsum  [8704,   +64*RS)
//   h     [17408,  +64*RS)
//   csum  [26112,  +64*RS)   (f16)
// After csv: reuse as f32 words: oh [0, 8704), oc [8704, 17408).

__device__ __forceinline__ uint4_ pack8(const float* v) {
  uint4_ r;
#pragma unroll
  for (int i = 0; i < 4; ++i)
    r[i] = __builtin_bit_cast(unsigned int,
                              __builtin_amdgcn_cvt_pkrtz(v[2 * i], v[2 * i + 1]));
  return r;
}

__device__ __forceinline__ void stage4(unsigned short* su, int baseH, int node,
                                       int k4, float4_ v) {
  uint2_ u;
  u[0] = __builtin_bit_cast(unsigned int, __builtin_amdgcn_cvt_pkrtz(v[0], v[1]));
  u[1] = __builtin_bit_cast(unsigned int, __builtin_amdgcn_cvt_pkrtz(v[2], v[3]));
  *reinterpret_cast<uint2_*>(&su[baseH + node * RS + k4]) = u;
}

__device__ __forceinline__ half8_ read_frag(const unsigned short* su, int baseH,
                                            int node, int kbase, int kq) {
  short8 s =
      *reinterpret_cast<const short8*>(&su[baseH + node * RS + kbase + kq * 8]);
  return __builtin_bit_cast(half8_, s);
}

__global__ __launch_bounds__(512, 4) void fused_mfma_kernel(
    const float* __restrict__ te, const float* __restrict__ h,
    const float* __restrict__ c, const int* __restrict__ row_ptr,
    const int* __restrict__ edge_src, const unsigned short* __restrict__ Bh,
    const float* __restrict__ bias, float* __restrict__ out_h,
    float* __restrict__ out_c) {
  __shared__ float4_ smem4[4352];  // 69632 bytes
  unsigned short* su = (unsigned short*)smem4;

  const int t = threadIdx.x;
  const int node0 = blockIdx.x * 64;

  // Phase 0: start gather dependency chain EARLY. Edge 0's rows go to regs;
  // edges 1-2 get a 1-dword warm touch so phase B hits L1/L2.
  const int nl = t >> 3;
  const int sub = t & 7;
  const int e0 = row_ptr[node0 + nl];
  const int e1 = row_ptr[node0 + nl + 1];
  int s0 = (e0 < e1) ? edge_src[e0] : 0;
  const bool has1 = (e0 + 1) < e1;
  const bool has2 = (e0 + 2) < e1;
  int s1 = edge_src[has1 ? e0 + 1 : 0];
  int s2 = edge_src[has2 ? e0 + 2 : 0];
  float4_ ph[4], pc[4];
  if (e0 < e1) {
    const float* hp = h + (size_t)s0 * HH + sub * 16;
    const float* cp = c + (size_t)s0 * HH + sub * 16;
#pragma unroll
    for (int i = 0; i < 4; ++i) {
      ph[i] = *reinterpret_cast<const float4_*>(hp + i * 4);
      pc[i] = *reinterpret_cast<const float4_*>(cp + i * 4);
    }
  }
  if (has1) {
    float w0 = h[(size_t)s1 * HH + sub * 16];
    float w1 = c[(size_t)s1 * HH + sub * 16];
    asm volatile("" ::"v"(w0), "v"(w1));  // keep the warming loads alive
  }
  if (has2) {
    float w0 = h[(size_t)s2 * HH + sub * 16];
    float w1 = c[(size_t)s2 * HH + sub * 16];
    asm volatile("" ::"v"(w0), "v"(w1));
  }

  // Phase A: stage te (nontemporal) and own-h (cached) as f16
#pragma unroll
  for (int i = 0; i < 4; ++i) {
    int q = t + i * 512;  // 0..2047 float4-chunks
    int node = q >> 5;
    int k4 = (q & 31) * 4;
    float4_ v = __builtin_nontemporal_load(
        reinterpret_cast<const float4_*>(te + (size_t)(node0 + node) * XX + k4));
    stage4(su, 0, node, k4, v);
    v = *reinterpret_cast<const float4_*>(h + (size_t)(node0 + node) * HH + k4);
    stage4(su, 17408, node, k4, v);
  }

  // Phase B: finish gather: 8 threads per node, 16 cols each.
  {
    float hs[16], cs[16];
#pragma unroll
    for (int j = 0; j < 16; ++j) {
      hs[j] = 0.f;
      cs[j] = 0.f;
    }
    if (e0 < e1) {
#pragma unroll
      for (int i = 0; i < 4; ++i)
#pragma unroll
        for (int j = 0; j < 4; ++j) {
          hs[i * 4 + j] += ph[i][j];
          cs[i * 4 + j] += pc[i][j];
        }
    }
    for (int e = e0 + 1; e < e1; ++e) {
      int s = edge_src[e];
      const float* hp = h + (size_t)s * HH + sub * 16;
      const float* cp = c + (size_t)s * HH + sub * 16;
#pragma unroll
      for (int i = 0; i < 4; ++i) {
        float4_ hv = *reinterpret_cast<const float4_*>(hp + i * 4);
        float4_ cv = *reinterpret_cast<const float4_*>(cp + i * 4);
#pragma unroll
        for (int j = 0; j < 4; ++j) {
          hs[i * 4 + j] += hv[j];
          cs[i * 4 + j] += cv[j];
        }
      }
    }
#pragma unroll
    for (int i = 0; i < 2; ++i) {
      int off = nl * RS + sub * 16 + i * 8;
      *reinterpret_cast<uint4_*>(&su[8704 + off]) = pack8(hs + i * 8);
      *reinterpret_cast<uint4_*>(&su[26112 + off]) = pack8(cs + i * 8);
    }
  }
  __syncthreads();

  const int lane = t & 63;
  const int wave = t >> 6;
  const int wc = wave * 16;  // column base (one 16-col group, all 4 gates)
  const int cl = lane & 15;
  const int kq = lane >> 4;
  const int col = wc + cl;

  // acc init = bias (MFMA C-in carries it through)
  float4_ acc[4][4];  // [gate][m]
#pragma unroll
  for (int g = 0; g < 4; ++g) {
    float b = bias[g * 128 + col];
#pragma unroll
    for (int m = 0; m < 4; ++m) acc[g][m] = (float4_){b, b, b, b};
  }

  for (int ks = 0; ks < 8; ++ks) {
    half8_ bh[4];
#pragma unroll
    for (int g = 0; g < 4; ++g) {
      size_t boff = (size_t)(((g * 8 + wave) * 8 + ks) * 512) + cl * 32 + kq * 8;
      bh[g] = __builtin_bit_cast(half8_,
                                 *reinterpret_cast<const short8*>(&Bh[boff]));
    }
    if (ks < 4) {
      int kbase = ks * 32;
#pragma unroll
      for (int m = 0; m < 4; ++m) {
        half8_ ah = read_frag(su, 0, m * 16 + cl, kbase, kq);
#pragma unroll
        for (int g = 0; g < 4; ++g)
          acc[g][m] = __builtin_amdgcn_mfma_f32_16x16x32_f16(ah, bh[g],
                                                             acc[g][m], 0, 0, 0);
      }
    } else {
      int kbase = (ks - 4) * 32;
#pragma unroll
      for (int m = 0; m < 4; ++m) {
        half8_ ah = read_frag(su, 8704, m * 16 + cl, kbase, kq);
        half8_ fh = read_frag(su, 17408, m * 16 + cl, kbase, kq);
#pragma unroll
        for (int g = 0; g < 3; ++g)
          acc[g][m] = __builtin_amdgcn_mfma_f32_16x16x32_f16(ah, bh[g],
                                                             acc[g][m], 0, 0, 0);
        acc[3][m] = __builtin_amdgcn_mfma_f32_16x16x32_f16(fh, bh[3],
                                                           acc[3][m], 0, 0, 0);
      }
    }
  }

  // Epilogue part 1: pull c_sum (f16) into regs before LDS reuse.
  float csv[4][4];
#pragma unroll
  for (int m = 0; m < 4; ++m)
#pragma unroll
    for (int r = 0; r < 4; ++r) {
      int row = m * 16 + kq * 4 + r;
      unsigned short hb = su[26112 + row * RS + col];
      csv[m][r] = (float)__builtin_bit_cast(_Float16, hb);
    }
  __syncthreads();  // all LDS reads done; safe to reuse for output assembly

  float* oh = (float*)smem4;         // words [0, 8704): h_new rows (stride RS)
  float* oc = (float*)smem4 + 8704;  // words [8704, 17408): c_new rows

  // Epilogue part 2: gates -> padded LDS assembly.
#pragma unroll
  for (int m = 0; m < 4; ++m)
#pragma unroll
    for (int r = 0; r < 4; ++r) {
      int rowl = m * 16 + kq * 4 + r;
      float ig = sigmoidf_(acc[0][m][r]);
      float og = sigmoidf_(acc[1][m][r]);
      float ug = tanhf_(acc[2][m][r]);
      float fg = sigmoidf_(acc[3][m][r]);
      float cn = fmaf(ig, ug, fg * csv[m][r]);
      int wadr = rowl * RS + col;
      oc[wadr] = cn;
      oh[wadr] = og * tanhf_(cn);
    }
  __syncthreads();

  // Stream outputs: fully coalesced float4 rows, nontemporal (never re-read).
#pragma unroll
  for (int i = 0; i < 4; ++i) {
    int q = t + i * 512;
    int rr = q >> 5;
    int k4 = (q & 31) * 4;
    int wadr = rr * RS + k4;
    __builtin_nontemporal_store(
        *reinterpret_cast<const float4_*>(&oh[wadr]),
        reinterpret_cast<float4_*>(out_h + (size_t)(node0 + rr) * HH + k4));
    __builtin_nontemporal_store(
        *reinterpret_cast<const float4_*>(&oc[wadr]),
        reinterpret_cast<float4_*>(out_c + (size_t)(node0 + rr) * HH + k4));
  }
}

extern "C" void kernel_launch(void* const* d_in, const int* in_sizes, int n_in,
                              void* d_out, int out_size, void* d_ws, size_t ws_size,
                              hipStream_t stream) {
  const float* te = (const float*)d_in[0];
  const float* h = (const float*)d_in[1];
  const float* c = (const float*)d_in[2];
  const int* src = (const int*)d_in[3];
  const int* dst = (const int*)d_in[4];
  const float* W_iou = (const float*)d_in[5];
  const float* U_iou = (const float*)d_in[6];
  const float* b_iou = (const float*)d_in[7];
  const float* U_f_w = (const float*)d_in[8];
  const float* U_f_b = (const float*)d_in[9];
  const float* W_f_w = (const float*)d_in[10];
  const float* b_f = (const float*)d_in[11];

  const int N = in_sizes[1] / HH;
  const int E = in_sizes[3];

  float* out_h = (float*)d_out;
  float* out_c = out_h + (size_t)N * HH;

  // workspace carve-up
  char* ws = (char*)d_ws;
  unsigned short* Bh = (unsigned short*)ws;              // 256 KB
  float* bias = (float*)(Bh + 4 * 8 * 8 * 16 * 4 * 8);   // 2 KB
  int* cnt = (int*)(bias + 512);                         // N ints
  int* row_ptr = cnt + N;                                // N+4 ints
  int* row_fill = row_ptr + N + 4;                       // N ints
  int* edge_src = row_fill + N;                          // E ints
  int* bsum = edge_src + E;                              // 256
  int* boff = bsum + 256;                                // 256

  hipMemsetAsync(cnt, 0, (size_t)N * sizeof(int), stream);

  hist_kernel<<<(E + 255) / 256, 256, 0, stream>>>(dst, cnt, E);
  scan_block_sum<<<N / 1024, 256, 0, stream>>>(cnt, bsum);
  scan_top<<<1, 256, 0, stream>>>(bsum, boff, row_ptr, N, E);
  scan_fill<<<N / 1024, 256, 0, stream>>>(cnt, boff, row_ptr, row_fill);
  fill_kernel<<<(E + 255) / 256, 256, 0, stream>>>(src, dst, row_fill, edge_src, E);

  prep_kernel<<<64, 256, 0, stream>>>(W_iou, U_iou, b_iou, U_f_w, U_f_b, W_f_w,
                                      b_f, Bh, bias);

  fused_mfma_kernel<<<N / 64, 512, 0, stream>>>(te, h, c, row_ptr, edge_src, Bh,
                                                bias, out_h, out_c);
}